// Round 3
// baseline (124.675 us; speedup 1.0000x reference)
//
#include <hip/hip_runtime.h>

// ---- types ----
typedef __bf16 bf8_t  __attribute__((ext_vector_type(8)));   // 8 x bf16 = 4 VGPR (MFMA A/B frag)
typedef float  f16v_t __attribute__((ext_vector_type(16)));  // 32x32 MFMA C/D frag
typedef unsigned short us4_t __attribute__((ext_vector_type(4)));

#define N_ROWS 4096
#define D_K    1024
#define TEMP_INV 20.0f   // 1 / 0.05

// fp32 -> bf16, round-to-nearest-even (no NaN in this problem)
__device__ __forceinline__ unsigned short f2bf(float f) {
    unsigned int u = __builtin_bit_cast(unsigned int, f);
    u += 0x7fffu + ((u >> 16) & 1u);
    return (unsigned short)(u >> 16);
}

// async global->LDS, 16B per lane. LDS dest must be wave-uniform base + lane*16.
__device__ __forceinline__ void gl_lds16(const __bf16* g, __bf16* l) {
    __builtin_amdgcn_global_load_lds(
        (const __attribute__((address_space(1))) unsigned int*)g,
        (__attribute__((address_space(3))) unsigned int*)l,
        16, 0, 0);
}

// ---------------- fused row normalize for both inputs: v / max(||v||, eps), fp32 -> bf16 ----
// blocks [0,4096) -> x, [4096,8192) -> y. One block (256 threads) per row of 1024 floats.
__global__ __launch_bounds__(256) void norm_rows_kernel(
    const float* __restrict__ x, const float* __restrict__ y,
    unsigned short* __restrict__ xb, unsigned short* __restrict__ yb)
{
    const int b   = blockIdx.x;
    const int row = b & (N_ROWS - 1);
    const float* in          = (b < N_ROWS) ? x  : y;
    unsigned short* out      = (b < N_ROWS) ? xb : yb;
    const int t = threadIdx.x;
    const float4* ip = (const float4*)(in + (size_t)row * D_K);
    float4 v = ip[t];
    float ss = v.x*v.x + v.y*v.y + v.z*v.z + v.w*v.w;
    #pragma unroll
    for (int off = 32; off > 0; off >>= 1)
        ss += __shfl_down(ss, off, 64);
    __shared__ float red[4];
    if ((t & 63) == 0) red[t >> 6] = ss;
    __syncthreads();
    float tot   = red[0] + red[1] + red[2] + red[3];
    float scale = 1.0f / fmaxf(sqrtf(tot), 1e-8f);
    us4_t o;
    o.x = f2bf(v.x * scale);
    o.y = f2bf(v.y * scale);
    o.z = f2bf(v.z * scale);
    o.w = f2bf(v.w * scale);
    *(us4_t*)(out + (size_t)row * D_K + t * 4) = o;
}

// ---------------- C = (A . B^T) * 20, A,B bf16 [4096][1024], C fp32 [4096][4096] ----------------
// 128x128 tile, BK=64, 4 waves (2x2), each wave a 2x2 grid of 32x32x16 MFMA, 4 k-substeps/iter.
// LDS XOR-swizzled: slot (row, s) holds global 8-elem k-group s ^ (row & 7); swizzle applied on
// the GLOBAL source address during staging (LDS dest of global_load_lds is fixed base+lane*16).
// Fragment ds_read_b128 start bank = 4*(g ^ (l31&7)) -> all 32 banks covered once per 8-lane phase.
// A/B frag layout (32x32x16): m/n = lane&31, k = (lane>>5)*8 + j.
// C/D layout (verified m74/m101): col = lane&31, row = (reg&3) + 8*(reg>>2) + 4*(lane>>5).
__global__ __launch_bounds__(256, 4) void cosim_gemm_kernel(
    const unsigned short* __restrict__ Aus,
    const unsigned short* __restrict__ Bus,
    float* __restrict__ C)
{
    const __bf16* A = (const __bf16*)Aus;
    const __bf16* B = (const __bf16*)Bus;

    __shared__ __align__(16) __bf16 As[128 * 64];   // 16 KB
    __shared__ __align__(16) __bf16 Bs[128 * 64];   // 16 KB

    const int t    = threadIdx.x;
    const int lane = t & 63;
    const int wid  = t >> 6;
    const int wm   = wid >> 1;   // 0..1  (M half)
    const int wn   = wid & 1;    // 0..1  (N half)
    const int bm   = blockIdx.x;
    const int bn   = blockIdx.y;

    // staging: thread t covers (row sr + 32*i, swizzled 8-elem group), 4 issues per matrix
    const int sr = t >> 3;                     // 0..31
    const int sg = (t & 7) ^ (sr & 7);         // swizzled source col-group
    const __bf16* ag = A + (size_t)(bm * 128 + sr) * D_K + sg * 8;
    const __bf16* bg = B + (size_t)(bn * 128 + sr) * D_K + sg * 8;
    __bf16* asd = As + t * 8;
    __bf16* bsd = Bs + t * 8;

    // fragment read bases: lane l31 = row within 32-block, half = k-half (8 elems each)
    const int l31  = lane & 31;
    const int half = lane >> 5;
    // row within LDS: arow(mi) = wm*64 + mi*32 + l31; (row&7) == (l31&7)
    const int rsw = l31 & 7;                   // swizzle key for this lane's rows

    f16v_t acc[2][2];
    #pragma unroll
    for (int mi = 0; mi < 2; mi++)
        #pragma unroll
        for (int ni = 0; ni < 2; ni++)
            #pragma unroll
            for (int r = 0; r < 16; r++)
                acc[mi][ni][r] = 0.f;

    for (int k0 = 0; k0 < D_K; k0 += 64) {
        #pragma unroll
        for (int i = 0; i < 4; i++) {
            gl_lds16(ag + (size_t)(32 * i) * D_K + k0, asd + 2048 * i);
            gl_lds16(bg + (size_t)(32 * i) * D_K + k0, bsd + 2048 * i);
        }
        __syncthreads();   // compiler emits s_waitcnt vmcnt(0) before s_barrier

        #pragma unroll
        for (int kk = 0; kk < 4; kk++) {
            const int g    = kk * 2 + half;        // global 8-elem k-group within the 64-wide stage
            const int slot = g ^ rsw;              // swizzled LDS slot
            bf8_t af[2], bfr[2];
            #pragma unroll
            for (int mi = 0; mi < 2; mi++)
                af[mi]  = *(const bf8_t*)(As + (wm * 64 + mi * 32 + l31) * 64 + slot * 8);
            #pragma unroll
            for (int ni = 0; ni < 2; ni++)
                bfr[ni] = *(const bf8_t*)(Bs + (wn * 64 + ni * 32 + l31) * 64 + slot * 8);
            #pragma unroll
            for (int mi = 0; mi < 2; mi++)
                #pragma unroll
                for (int ni = 0; ni < 2; ni++)
                    acc[mi][ni] = __builtin_amdgcn_mfma_f32_32x32x16_bf16(
                        af[mi], bfr[ni], acc[mi][ni], 0, 0, 0);
        }

        __syncthreads();   // protect LDS before next stage overwrites
    }

    // epilogue: col = lane&31, row = (reg&3) + 8*(reg>>2) + 4*half
    #pragma unroll
    for (int mi = 0; mi < 2; mi++) {
        #pragma unroll
        for (int ni = 0; ni < 2; ni++) {
            const int col = bn * 128 + wn * 64 + ni * 32 + l31;
            const int rb  = bm * 128 + wm * 64 + mi * 32 + 4 * half;
            #pragma unroll
            for (int reg = 0; reg < 16; reg++) {
                const int row = rb + (reg & 3) + 8 * (reg >> 2);
                C[(size_t)row * N_ROWS + col] = acc[mi][ni][reg] * TEMP_INV;
            }
        }
    }
}

extern "C" void kernel_launch(void* const* d_in, const int* in_sizes, int n_in,
                              void* d_out, int out_size, void* d_ws, size_t ws_size,
                              hipStream_t stream)
{
    const float* x = (const float*)d_in[0];
    const float* y = (const float*)d_in[1];
    float* out = (float*)d_out;

    unsigned short* xb = (unsigned short*)d_ws;                 // 8 MB
    unsigned short* yb = xb + (size_t)N_ROWS * D_K;             // 8 MB

    norm_rows_kernel<<<2 * N_ROWS, 256, 0, stream>>>(x, y, xb, yb);

    dim3 grid(N_ROWS / 128, N_ROWS / 128);
    cosim_gemm_kernel<<<grid, 256, 0, stream>>>(xb, yb, out);
}

// Round 4
// 122.815 us; speedup vs baseline: 1.0151x; 1.0151x over previous
//
#include <hip/hip_runtime.h>

// ---- types ----
typedef __bf16 bf8_t  __attribute__((ext_vector_type(8)));   // 8 x bf16 = 4 VGPR (MFMA A/B frag)
typedef float  f4_t   __attribute__((ext_vector_type(4)));   // MFMA C/D frag
typedef unsigned short us4_t __attribute__((ext_vector_type(4)));

#define N_ROWS 4096
#define D_K    1024
#define TEMP_INV 20.0f   // 1 / 0.05  (folded into x-normalization)

// fp32 -> bf16, round-to-nearest-even (no NaN in this problem)
__device__ __forceinline__ unsigned short f2bf(float f) {
    unsigned int u = __builtin_bit_cast(unsigned int, f);
    u += 0x7fffu + ((u >> 16) & 1u);
    return (unsigned short)(u >> 16);
}

// async global->LDS, 16B per lane. LDS dest must be wave-uniform base + lane*16.
__device__ __forceinline__ void gl_lds16(const __bf16* g, __bf16* l) {
    __builtin_amdgcn_global_load_lds(
        (const __attribute__((address_space(1))) unsigned int*)g,
        (__attribute__((address_space(3))) unsigned int*)l,
        16, 0, 0);
}

// ---------------- fused row normalize for both inputs: v / max(||v||, eps), fp32 -> bf16 ----
// blocks [0,4096) -> x (scaled by 1/TEMP), [4096,8192) -> y. One block per row of 1024 floats.
__global__ __launch_bounds__(256) void norm_rows_kernel(
    const float* __restrict__ x, const float* __restrict__ y,
    unsigned short* __restrict__ xb, unsigned short* __restrict__ yb)
{
    const int b   = blockIdx.x;
    const int row = b & (N_ROWS - 1);
    const bool isx = (b < N_ROWS);
    const float* in     = isx ? x  : y;
    unsigned short* out = isx ? xb : yb;
    const float post    = isx ? TEMP_INV : 1.0f;
    const int t = threadIdx.x;
    const float4* ip = (const float4*)(in + (size_t)row * D_K);
    float4 v = ip[t];
    float ss = v.x*v.x + v.y*v.y + v.z*v.z + v.w*v.w;
    #pragma unroll
    for (int off = 32; off > 0; off >>= 1)
        ss += __shfl_down(ss, off, 64);
    __shared__ float red[4];
    if ((t & 63) == 0) red[t >> 6] = ss;
    __syncthreads();
    float tot   = red[0] + red[1] + red[2] + red[3];
    float scale = post / fmaxf(sqrtf(tot), 1e-8f);
    us4_t o;
    o.x = f2bf(v.x * scale);
    o.y = f2bf(v.y * scale);
    o.z = f2bf(v.z * scale);
    o.w = f2bf(v.w * scale);
    *(us4_t*)(out + (size_t)row * D_K + t * 4) = o;
}

// ---------------- C = A . B^T, A,B bf16 [4096][1024], C fp32 [4096][4096] ----------------
// (1/TEMP pre-folded into A.)  R2-verified config: 128x128 tile, BK=64, 4 waves (2x2),
// each wave 4x4 grid of 16x16x32 MFMA, 2 k-substeps/iter.
// LDS XOR-swizzled: slot (row, s) holds global 8-elem k-group s ^ (row & 7); swizzle applied
// on the GLOBAL source address during staging (LDS dest of global_load_lds is fixed
// base + lane*16). Fragment ds_read_b128 start bank = 4*(g ^ (l15&7)) -> measured ZERO
// SQ_LDS_BANK_CONFLICT in this exact configuration (R2). Do not switch to 32x32 MFMA:
// measured 4.19M conflict cycles + 8% regression (R3) despite identical-looking bank math.
__global__ __launch_bounds__(256, 4) void cosim_gemm_kernel(
    const unsigned short* __restrict__ Aus,
    const unsigned short* __restrict__ Bus,
    float* __restrict__ C)
{
    const __bf16* A = (const __bf16*)Aus;
    const __bf16* B = (const __bf16*)Bus;

    __shared__ __align__(16) __bf16 As[128 * 64];   // 16 KB
    __shared__ __align__(16) __bf16 Bs[128 * 64];   // 16 KB

    const int t    = threadIdx.x;
    const int lane = t & 63;
    const int wid  = t >> 6;
    const int wm   = wid >> 1;   // 0..1  (M half)
    const int wn   = wid & 1;    // 0..1  (N half)
    const int bm   = blockIdx.x;
    const int bn   = blockIdx.y;

    // staging: thread t covers (row sr + 32*i, swizzled 8-elem group), 4 issues per matrix
    const int sr = t >> 3;                     // 0..31
    const int sg = (t & 7) ^ (sr & 7);         // swizzled source col-group
    const __bf16* ag = A + (size_t)(bm * 128 + sr) * D_K + sg * 8;
    const __bf16* bg = B + (size_t)(bn * 128 + sr) * D_K + sg * 8;
    __bf16* asd = As + t * 8;
    __bf16* bsd = Bs + t * 8;

    // fragment read bases: row rr needs global group (kk*4 + quad) at LDS slot (group ^ (rr&7))
    const int l15  = lane & 15;
    const int quad = lane >> 4;
    const int g0 = quad       ^ (l15 & 7);     // kk = 0
    const int g1 = (quad + 4) ^ (l15 & 7);     // kk = 1
    const __bf16* ar0 = As + (wm * 64 + l15) * 64 + g0 * 8;
    const __bf16* ar1 = As + (wm * 64 + l15) * 64 + g1 * 8;
    const __bf16* br0 = Bs + (wn * 64 + l15) * 64 + g0 * 8;
    const __bf16* br1 = Bs + (wn * 64 + l15) * 64 + g1 * 8;

    f4_t acc[4][4];
    #pragma unroll
    for (int mi = 0; mi < 4; mi++)
        #pragma unroll
        for (int ni = 0; ni < 4; ni++) {
            acc[mi][ni][0] = 0.f; acc[mi][ni][1] = 0.f;
            acc[mi][ni][2] = 0.f; acc[mi][ni][3] = 0.f;
        }

    for (int k0 = 0; k0 < D_K; k0 += 64) {
        #pragma unroll
        for (int i = 0; i < 4; i++) {
            gl_lds16(ag + (size_t)(32 * i) * D_K + k0, asd + 2048 * i);
            gl_lds16(bg + (size_t)(32 * i) * D_K + k0, bsd + 2048 * i);
        }
        __syncthreads();   // compiler emits s_waitcnt vmcnt(0) before s_barrier

        // kk = 0
        {
            bf8_t af[4], bfr[4];
            #pragma unroll
            for (int mi = 0; mi < 4; mi++) af[mi]  = *(const bf8_t*)(ar0 + mi * 16 * 64);
            #pragma unroll
            for (int ni = 0; ni < 4; ni++) bfr[ni] = *(const bf8_t*)(br0 + ni * 16 * 64);
            #pragma unroll
            for (int mi = 0; mi < 4; mi++)
                #pragma unroll
                for (int ni = 0; ni < 4; ni++)
                    acc[mi][ni] = __builtin_amdgcn_mfma_f32_16x16x32_bf16(
                        af[mi], bfr[ni], acc[mi][ni], 0, 0, 0);
        }
        // kk = 1
        {
            bf8_t af[4], bfr[4];
            #pragma unroll
            for (int mi = 0; mi < 4; mi++) af[mi]  = *(const bf8_t*)(ar1 + mi * 16 * 64);
            #pragma unroll
            for (int ni = 0; ni < 4; ni++) bfr[ni] = *(const bf8_t*)(br1 + ni * 16 * 64);
            #pragma unroll
            for (int mi = 0; mi < 4; mi++)
                #pragma unroll
                for (int ni = 0; ni < 4; ni++)
                    acc[mi][ni] = __builtin_amdgcn_mfma_f32_16x16x32_bf16(
                        af[mi], bfr[ni], acc[mi][ni], 0, 0, 0);
        }

        __syncthreads();   // protect LDS before next stage overwrites
    }

    // epilogue: C/D layout col = lane&15, row = (lane>>4)*4 + reg  [m89/m91 verified]
    #pragma unroll
    for (int mi = 0; mi < 4; mi++) {
        #pragma unroll
        for (int ni = 0; ni < 4; ni++) {
            const int row = bm * 128 + wm * 64 + mi * 16 + quad * 4;
            const int col = bn * 128 + wn * 64 + ni * 16 + l15;
            #pragma unroll
            for (int r = 0; r < 4; r++)
                C[(size_t)(row + r) * N_ROWS + col] = acc[mi][ni][r];
        }
    }
}

extern "C" void kernel_launch(void* const* d_in, const int* in_sizes, int n_in,
                              void* d_out, int out_size, void* d_ws, size_t ws_size,
                              hipStream_t stream)
{
    const float* x = (const float*)d_in[0];
    const float* y = (const float*)d_in[1];
    float* out = (float*)d_out;

    unsigned short* xb = (unsigned short*)d_ws;                 // 8 MB
    unsigned short* yb = xb + (size_t)N_ROWS * D_K;             // 8 MB

    norm_rows_kernel<<<2 * N_ROWS, 256, 0, stream>>>(x, y, xb, yb);

    dim3 grid(N_ROWS / 128, N_ROWS / 128);
    cosim_gemm_kernel<<<grid, 256, 0, stream>>>(xb, yb, out);
}